// Round 10
// baseline (358.988 us; speedup 1.0000x reference)
//
#include <hip/hip_runtime.h>
#include <hip/hip_bf16.h>

#define D_MODEL 4096
#define VOCAB 50257
#define NUM_SEQS 32
#define NT 1571    // ceil(VOCAB/32) vocab tiles of 32 rows
#define BK 256     // K per staged chunk
#define NCH (D_MODEL / BK)   // 16 chunks
#define SROW 260   // padded LDS row stride (floats)

typedef __attribute__((ext_vector_type(8))) short bf16x8;
typedef __attribute__((ext_vector_type(16))) float f32x16;

// ws layout:
//   [0,128)              idx[32] int
//   [4096, +256KB)       hBh [512][32][8] short  (h hi bf16, MFMA-B-frag order)
//   [266240, +256KB)     hBl [512][32][8] short  (h lo bf16)
//   [528384, +402KB)     wbest [NT][32] u64 per-tile per-seq argmax keys

__device__ __forceinline__ void cvt2(float f, short* hi, short* lo) {
  union { __hip_bfloat16 b; short s; } h, l;
  h.b = __float2bfloat16(f);                 // RNE
  float hf = __bfloat162float(h.b);
  l.b = __float2bfloat16(f - hf);            // residual, RNE
  *hi = h.s; *lo = l.s;
}

__global__ void k_prep(const int* __restrict__ lens, int* __restrict__ idx) {
  if (threadIdx.x == 0) {
    int run = 0;
    for (int s = 0; s < NUM_SEQS; ++s) { run += lens[s]; idx[s] = run - 1; }
  }
}

// 256 blocks x 512: thread g -> (s = g>>12, k = g&4095). Coalesced hs reads.
__global__ void k_gather(const float* __restrict__ hs, const int* __restrict__ idx,
                         short* __restrict__ hBh, short* __restrict__ hBl) {
  int g = blockIdx.x * 512 + threadIdx.x;
  int s = g >> 12, k = g & 4095;
  float v = hs[(size_t)idx[s] * D_MODEL + k];
  short hi, lo; cvt2(v, &hi, &lo);
  int off = ((k >> 3) * 32 + s) * 8 + (k & 7);  // [k/8][s][k%8]
  hBh[off] = hi; hBl[off] = lo;
}

// grid NT x 256 (4 waves). Block = one 32-row tile, full K. Cooperative
// staging: per pass, each wave reads 1KB CONTIGUOUS from one W row (few,
// long DRAM bursts) into padded LDS double-buffer. Waves K-split each chunk
// (64 k each), r5's proven MFMA/cvt2 body, B from L2-hot planes. Partials
// combined in LDS at the end. One barrier per chunk.
__global__ __launch_bounds__(256, 2) void k_mfma(const float* __restrict__ W,
    const short* __restrict__ hBh, const short* __restrict__ hBl,
    unsigned long long* __restrict__ wbest) {
  __shared__ float lds[2][32 * SROW];
  __shared__ float comb[3][64][17];

  const int tid = threadIdx.x;
  const int lane = tid & 63;
  const int wv = tid >> 6;        // wave id 0..3
  const int half = lane >> 5;
  const int r32 = lane & 31;
  const int tile = blockIdx.x;

  // staging coords: pass p stages row p*4+wv, this lane covers float4 #scol
  const int scol = tid & 63;
  const float* bases[8];
#pragma unroll
  for (int p = 0; p < 8; ++p) {
    int wr = min(tile * 32 + p * 4 + wv, VOCAB - 1);
    bases[p] = W + (size_t)wr * D_MODEL + scol * 4;
  }

  // compute-side B pointers (L2-hot planes)
  const short* bph = hBh + ((size_t)half * 32 + r32) * 8;  // + 512*t per k-step
  const short* bpl = hBl + ((size_t)half * 32 + r32) * 8;

  f32x16 accA, accB;
#pragma unroll
  for (int i = 0; i < 16; ++i) { accA[i] = 0.f; accB[i] = 0.f; }

  float4 streg[8];
  // prologue: stage chunk 0
#pragma unroll
  for (int p = 0; p < 8; ++p) streg[p] = *(const float4*)(bases[p]);
#pragma unroll
  for (int p = 0; p < 8; ++p)
    *(float4*)&lds[0][(p * 4 + wv) * SROW + scol * 4] = streg[p];
  __syncthreads();

  // preload first B fragment (wave's k-step 0 = wv*4)
  bf16x8 bh = *(const bf16x8*)(bph + 512 * (wv * 4));
  bf16x8 bl = *(const bf16x8*)(bpl + 512 * (wv * 4));

  int buf = 0;
#pragma unroll 1
  for (int c = 0; c < NCH; ++c) {
    if (c + 1 < NCH) {  // issue next chunk's loads early (hide under compute)
#pragma unroll
      for (int p = 0; p < 8; ++p)
        streg[p] = *(const float4*)(bases[p] + (c + 1) * BK);
    }
#pragma unroll
    for (int j = 0; j < 4; ++j) {
      // next B fragment (depth-1 roll; wrap harmless)
      int tn = (j < 3) ? (c * 16 + wv * 4 + j + 1)
                       : ((c + 1 < NCH) ? ((c + 1) * 16 + wv * 4) : 0);
      bf16x8 nbh = *(const bf16x8*)(bph + 512 * tn);
      bf16x8 nbl = *(const bf16x8*)(bpl + 512 * tn);
      // A fragment from LDS: row=r32, k = wv*64 + j*16 + half*8 .. +8
      const float* ap = &lds[buf][r32 * SROW + wv * 64 + j * 16 + half * 8];
      float4 a0 = *(const float4*)(ap);
      float4 a1 = *(const float4*)(ap + 4);

      float fa[8] = {a0.x, a0.y, a0.z, a0.w, a1.x, a1.y, a1.z, a1.w};
      bf16x8 ahi, alo;
#pragma unroll
      for (int e = 0; e < 8; ++e) {
        short hi, lo; cvt2(fa[e], &hi, &lo);
        ahi[e] = hi; alo[e] = lo;
      }
      accA = __builtin_amdgcn_mfma_f32_32x32x16_bf16(ahi, bh, accA, 0, 0, 0);
      accB = __builtin_amdgcn_mfma_f32_32x32x16_bf16(ahi, bl, accB, 0, 0, 0);
      accA = __builtin_amdgcn_mfma_f32_32x32x16_bf16(alo, bh, accA, 0, 0, 0);
      bh = nbh; bl = nbl;
    }
    if (c + 1 < NCH) {  // write staged chunk to the other buffer
#pragma unroll
      for (int p = 0; p < 8; ++p)
        *(float4*)&lds[buf ^ 1][(p * 4 + wv) * SROW + scol * 4] = streg[p];
    }
    __syncthreads();
    buf ^= 1;
  }

#pragma unroll
  for (int i = 0; i < 16; ++i) accA[i] += accB[i];

  // cross-wave combine (fixed order -> deterministic)
  if (wv > 0) {
#pragma unroll
    for (int i = 0; i < 16; ++i) comb[wv - 1][lane][i] = accA[i];
  }
  __syncthreads();
  if (wv == 0) {
#pragma unroll
    for (int w = 0; w < 3; ++w)
#pragma unroll
      for (int i = 0; i < 16; ++i) accA[i] += comb[w][lane][i];

    // C layout: col(seq)=lane&31, row=(r&3)+8*(r>>2)+4*half
    unsigned long long best = 0ull;
#pragma unroll
    for (int r = 0; r < 16; ++r) {
      int row = (r & 3) + 8 * (r >> 2) + 4 * half;
      int v = tile * 32 + row;
      if (v < VOCAB) {
        unsigned u = __float_as_uint(accA[r]);
        u = (u & 0x80000000u) ? ~u : (u | 0x80000000u);
        unsigned long long key = ((unsigned long long)u << 32) | (unsigned)(~v);
        if (key > best) best = key;
      }
    }
    unsigned long long o = __shfl_xor(best, 32, 64);
    if (o > best) best = o;
    if (half == 0) wbest[(size_t)tile * 32 + r32] = best;  // lane r32 = seq r32
  }
}

// 32 blocks x 256: block = seq; scan NT tile-keys, first-occurrence tie-break.
__global__ __launch_bounds__(256) void k_final(
    const unsigned long long* __restrict__ wbest, int* __restrict__ out) {
  int s = blockIdx.x;
  unsigned long long best = 0ull;
  for (int i = threadIdx.x; i < NT; i += 256) {
    unsigned long long k = wbest[(size_t)i * 32 + s];
    if (k > best) best = k;
  }
#pragma unroll
  for (int off = 32; off > 0; off >>= 1) {
    unsigned long long o = __shfl_xor(best, off, 64);
    if (o > best) best = o;
  }
  __shared__ unsigned long long lred[4];
  if ((threadIdx.x & 63) == 0) lred[threadIdx.x >> 6] = best;
  __syncthreads();
  if (threadIdx.x == 0) {
#pragma unroll
    for (int i = 1; i < 4; ++i) if (lred[i] > best) best = lred[i];
    out[s] = (int)(~(unsigned)(best & 0xFFFFFFFFull));
  }
}

extern "C" void kernel_launch(void* const* d_in, const int* in_sizes, int n_in,
                              void* d_out, int out_size, void* d_ws, size_t ws_size,
                              hipStream_t stream) {
  const float* hs  = (const float*)d_in[0];   // [16384][4096] f32
  const float* W   = (const float*)d_in[1];   // [50257][4096] f32
  const int* lens  = (const int*)d_in[2];     // [32] i32

  char* ws = (char*)d_ws;
  int* idx = (int*)ws;
  short* hBh = (short*)(ws + 4096);
  short* hBl = (short*)(ws + 266240);
  unsigned long long* wbest = (unsigned long long*)(ws + 528384);
  int* out = (int*)d_out;

  k_prep<<<1, 64, 0, stream>>>(lens, idx);
  k_gather<<<256, 512, 0, stream>>>(hs, idx, hBh, hBl);
  k_mfma<<<NT, 256, 0, stream>>>(W, hBh, hBl, wbest);
  k_final<<<NUM_SEQS, 256, 0, stream>>>(wbest, out);
}

// Round 11
// 203.140 us; speedup vs baseline: 1.7672x; 1.7672x over previous
//
#include <hip/hip_runtime.h>
#include <hip/hip_bf16.h>

#define D_MODEL 4096
#define VOCAB 50257
#define NUM_SEQS 32
#define NT 1571  // ceil(VOCAB/32) vocab tiles of 32 rows

typedef __attribute__((ext_vector_type(8))) short bf16x8;
typedef __attribute__((ext_vector_type(16))) float f32x16;

// ws layout:
//   [0,128)              idx[32] int
//   [4096, +256KB)       hBh [512][32][8] short  (h hi bf16, MFMA-B-frag order)
//   [266240, +256KB)     hBl [512][32][8] short  (h lo bf16)
//   [528384, +402KB)     wbest [NT][32] u64 per-tile per-seq argmax keys

__device__ __forceinline__ void cvt2(float f, short* hi, short* lo) {
  union { __hip_bfloat16 b; short s; } h, l;
  h.b = __float2bfloat16(f);                 // RNE
  float hf = __bfloat162float(h.b);
  l.b = __float2bfloat16(f - hf);            // residual, RNE
  *hi = h.s; *lo = l.s;
}

__global__ void k_prep(const int* __restrict__ lens, int* __restrict__ idx) {
  if (threadIdx.x == 0) {
    int run = 0;
    for (int s = 0; s < NUM_SEQS; ++s) { run += lens[s]; idx[s] = run - 1; }
  }
}

// 256 blocks x 512: thread g -> (s = g>>12, k = g&4095). Coalesced hs reads.
__global__ void k_gather(const float* __restrict__ hs, const int* __restrict__ idx,
                         short* __restrict__ hBh, short* __restrict__ hBl) {
  int g = blockIdx.x * 512 + threadIdx.x;
  int s = g >> 12, k = g & 4095;
  float v = hs[(size_t)idx[s] * D_MODEL + k];
  short hi, lo; cvt2(v, &hi, &lo);
  int off = ((k >> 3) * 32 + s) * 8 + (k & 7);  // [k/8][s][k%8]
  hBh[off] = hi; hBl[off] = lo;
}

// grid NT x 64. Wave = one 32-vocab x 32-seq tile, full K=4096.
// A = W tile (lane: row=l&31, k=(l>>5)*8+e), converted f32->bf16 hi/lo on the fly.
// B = h (lane: col(seq)=l&31, k=(l>>5)*8+e) from precomputed hi/lo planes (L2-hot).
// Simple depth-2 A roll / depth-1 B roll -- empirically optimal (r6-r10 all
// deeper/restructured variants regressed; compiler schedules this body best).
__global__ __launch_bounds__(64) void k_mfma(const float* __restrict__ W,
    const short* __restrict__ hBh, const short* __restrict__ hBl,
    unsigned long long* __restrict__ wbest) {
  const int lane = threadIdx.x;
  const int half = lane >> 5;
  const int r32 = lane & 31;
  const int tile = blockIdx.x;
  const int wrow = min(tile * 32 + r32, VOCAB - 1);
  const float* wp = W + (size_t)wrow * D_MODEL + half * 8;
  const short* bph = hBh + ((size_t)half * 32 + r32) * 8;  // step stride 512 shorts
  const short* bpl = hBl + ((size_t)half * 32 + r32) * 8;

  f32x16 accA, accB;
#pragma unroll
  for (int i = 0; i < 16; ++i) { accA[i] = 0.f; accB[i] = 0.f; }

  // A prefetch depth 2 (HBM stream), B depth 1 (L2 stream)
  float4 a0 = *(const float4*)(wp);
  float4 a1 = *(const float4*)(wp + 4);
  float4 p0 = *(const float4*)(wp + 16);
  float4 p1 = *(const float4*)(wp + 20);
  bf16x8 bh = *(const bf16x8*)(bph);
  bf16x8 bl = *(const bf16x8*)(bpl);

#pragma unroll 1
  for (int t = 0; t < 256; ++t) {
    const int t2 = (t + 2 < 256) ? t + 2 : 0;
    const int t1 = (t + 1 < 256) ? t + 1 : 0;
    float4 n0 = *(const float4*)(wp + 16 * t2);
    float4 n1 = *(const float4*)(wp + 16 * t2 + 4);
    bf16x8 nbh = *(const bf16x8*)(bph + 512 * t1);
    bf16x8 nbl = *(const bf16x8*)(bpl + 512 * t1);

    float fa[8] = {a0.x, a0.y, a0.z, a0.w, a1.x, a1.y, a1.z, a1.w};
    bf16x8 ahi, alo;
#pragma unroll
    for (int e = 0; e < 8; ++e) {
      short hi, lo; cvt2(fa[e], &hi, &lo);
      ahi[e] = hi; alo[e] = lo;
    }

    accA = __builtin_amdgcn_mfma_f32_32x32x16_bf16(ahi, bh, accA, 0, 0, 0);
    accB = __builtin_amdgcn_mfma_f32_32x32x16_bf16(ahi, bl, accB, 0, 0, 0);
    accA = __builtin_amdgcn_mfma_f32_32x32x16_bf16(alo, bh, accA, 0, 0, 0);

    a0 = p0; a1 = p1; p0 = n0; p1 = n1; bh = nbh; bl = nbl;
  }

#pragma unroll
  for (int i = 0; i < 16; ++i) accA[i] += accB[i];

  // C layout: col(seq)=lane&31, row=(r&3)+8*(r>>2)+4*half
  unsigned long long best = 0ull;
#pragma unroll
  for (int r = 0; r < 16; ++r) {
    int row = (r & 3) + 8 * (r >> 2) + 4 * half;
    int v = tile * 32 + row;
    if (v < VOCAB) {
      unsigned u = __float_as_uint(accA[r]);
      u = (u & 0x80000000u) ? ~u : (u | 0x80000000u);
      unsigned long long key = ((unsigned long long)u << 32) | (unsigned)(~v);
      if (key > best) best = key;
    }
  }
  unsigned long long o = __shfl_xor(best, 32, 64);
  if (o > best) best = o;
  if (half == 0) wbest[(size_t)tile * 32 + r32] = best;
}

// 32 blocks x 256: block = seq; scan NT tile-keys, first-occurrence tie-break.
__global__ __launch_bounds__(256) void k_final(
    const unsigned long long* __restrict__ wbest, int* __restrict__ out) {
  int s = blockIdx.x;
  unsigned long long best = 0ull;
  for (int i = threadIdx.x; i < NT; i += 256) {
    unsigned long long k = wbest[(size_t)i * 32 + s];
    if (k > best) best = k;
  }
#pragma unroll
  for (int off = 32; off > 0; off >>= 1) {
    unsigned long long o = __shfl_xor(best, off, 64);
    if (o > best) best = o;
  }
  __shared__ unsigned long long lred[4];
  if ((threadIdx.x & 63) == 0) lred[threadIdx.x >> 6] = best;
  __syncthreads();
  if (threadIdx.x == 0) {
#pragma unroll
    for (int i = 1; i < 4; ++i) if (lred[i] > best) best = lred[i];
    out[s] = (int)(~(unsigned)(best & 0xFFFFFFFFull));
  }
}

extern "C" void kernel_launch(void* const* d_in, const int* in_sizes, int n_in,
                              void* d_out, int out_size, void* d_ws, size_t ws_size,
                              hipStream_t stream) {
  const float* hs  = (const float*)d_in[0];   // [16384][4096] f32
  const float* W   = (const float*)d_in[1];   // [50257][4096] f32
  const int* lens  = (const int*)d_in[2];     // [32] i32

  char* ws = (char*)d_ws;
  int* idx = (int*)ws;
  short* hBh = (short*)(ws + 4096);
  short* hBl = (short*)(ws + 266240);
  unsigned long long* wbest = (unsigned long long*)(ws + 528384);
  int* out = (int*)d_out;

  k_prep<<<1, 64, 0, stream>>>(lens, idx);
  k_gather<<<256, 512, 0, stream>>>(hs, idx, hBh, hBl);
  k_mfma<<<NT, 64, 0, stream>>>(W, hBh, hBl, wbest);
  k_final<<<NUM_SEQS, 256, 0, stream>>>(wbest, out);
}